// Round 5
// baseline (478.166 us; speedup 1.0000x reference)
//
#include <hip/hip_runtime.h>
#include <hip/hip_bf16.h>

typedef unsigned short u16;
typedef __attribute__((ext_vector_type(8))) short bf16x8;   // 8 bf16 = 4 VGPRs
typedef __attribute__((ext_vector_type(4))) float f32x4;

#define EPSN 1e-9f

// ---------- helpers ----------

__device__ __forceinline__ u16 f2bf(float f) {
    union { float f; unsigned int u; } c; c.f = f;
    unsigned int u = c.u;
    unsigned int r = (u + 0x7FFFu + ((u >> 16) & 1u)) >> 16;   // RNE
    return (u16)r;
}

__device__ __forceinline__ void load16_to_lds(const void* g, void* l) {
    __builtin_amdgcn_global_load_lds(
        (const __attribute__((address_space(1))) void*)g,
        (__attribute__((address_space(3))) void*)l,
        16, 0, 0);
}

// ---------- K1: per-row L2 normalize + cast to bf16, wave-per-row, X and W fused ----
__global__ __launch_bounds__(256) void normalize_cast2(
    const float* __restrict__ X, const float* __restrict__ W,
    u16* __restrict__ XO, u16* __restrict__ WO, int ncols, int nxrows, int nrt) {
    const int lane = threadIdx.x & 63;
    const int r = blockIdx.x * 4 + (threadIdx.x >> 6);
    if (r >= nrt) return;
    const float* src; u16* dst; size_t row;
    if (r < nxrows) { src = X; dst = XO; row = r; }
    else            { src = W; dst = WO; row = r - nxrows; }

    const float4* xr = (const float4*)(src + row * (size_t)ncols);
    const int nq = ncols >> 2;

    float4 v[8];
    float ss = 0.f;
    #pragma unroll
    for (int q = 0; q < 8; ++q) {
        int i = lane + q * 64;
        if (i < nq) {
            v[q] = xr[i];
            ss += v[q].x*v[q].x + v[q].y*v[q].y + v[q].z*v[q].z + v[q].w*v[q].w;
        }
    }
    #pragma unroll
    for (int o = 32; o > 0; o >>= 1) ss += __shfl_xor(ss, o);
    const float s = 1.f / (sqrtf(ss) + EPSN);

    ushort4* yr = (ushort4*)(dst + row * (size_t)ncols);
    #pragma unroll
    for (int q = 0; q < 8; ++q) {
        int i = lane + q * 64;
        if (i < nq) {
            ushort4 o4;
            o4.x = f2bf(v[q].x * s); o4.y = f2bf(v[q].y * s);
            o4.z = f2bf(v[q].z * s); o4.w = f2bf(v[q].w * s);
            yr[i] = o4;
        }
    }
}

// ---------- K2: 256x256 8-phase bf16 MFMA GEMM + fused relu/pow epilogue ----------
// m201-template port, 3rd attempt — derived schedule (see session notes):
//  * 512 thr = 8 waves (2m x 4n); per-wave output = rows {mh*128+wm*64+0..63},
//    cols {nh*128+wn*32+0..31} over quadrants q=(mh,nh) -> each phase touches
//    exactly one A-half and one B-half, freeing each half 1 phase before re-stage.
//  * 8 phases / 2 K-tiles; per phase: ds_reads (12 or 4) -> stage ONE half-tile
//    (2 global_load_lds) -> barrier -> lgkmcnt(0) -> 16 MFMA -> [vmcnt(4) at q3]
//    -> barrier. Stage targets: q0 other.Ab<-t+1, q1 other.Bb<-t+1,
//    q2 self.At<-t+2, q3 self.Bt<-t+2 (each region dead since previous phase).
//  * FIFO per tile = At,Bt,Ab,Bb -> vmcnt(4) at q3 retires exactly the next
//    K-tile; issue->wait distance 3-6 phases; never below 2 halves in flight.
//  * LDS halves are contiguous 16KB (global_load_lds-legal); bank swizzle
//    slot = chunk ^ (row&7) on the GLOBAL source + ds_read addr (round-0 proven).
__global__ __launch_bounds__(512, 2) void gemm_softhebb(
    const u16* __restrict__ A, const u16* __restrict__ B,
    const float* __restrict__ logprior, const float* __restrict__ lambp,
    float* __restrict__ Ul, float* __restrict__ rowsum,
    int M, int N, int K) {
    __shared__ __align__(16) u16 lA[32768];   // [2 buf][2 half][128 r][8 ch][8]
    __shared__ __align__(16) u16 lB[32768];

    const int tid  = threadIdx.x;
    const int lane = tid & 63;
    const int wid  = tid >> 6;
    const int wm   = wid >> 2;     // 0..1
    const int wn   = wid & 3;      // 0..3

    // XCD chunked swizzle: 64 consecutive wg (8 full row-panels) per XCD
    int wg = blockIdx.x;
    wg = (wg & 7) * 64 + (wg >> 3);
    const int ntn = N >> 8;                    // 8
    const int tm = wg / ntn, tn = wg - tm * ntn;
    const int row0 = tm << 8, col0 = tn << 8;

    // staging thread geometry: thread covers rows {srow, srow+64} of a half,
    // chunk c = (tid&7) ^ (srow&7) (XOR involution; matched on the read side)
    const int srow = tid >> 3;
    const int scol = ((tid & 7) ^ (srow & 7)) * 8;
    const u16* Ab_ = A + (size_t)row0 * K;
    const u16* Bb_ = B + (size_t)col0 * K;
    const int nt = K >> 6;                     // 32 (even)

    auto stageA = [&](u16* lbase, int halfsel, int T) {
        const int koff = (T < nt) ? (T << 6) : 0;
        const u16* g = Ab_ + (size_t)(halfsel * 128 + srow) * K + koff + scol;
        u16* d = lbase + halfsel * 8192 + tid * 8;
        load16_to_lds(g, d);
        load16_to_lds(g + (size_t)64 * K, d + 4096);
    };
    auto stageB = [&](u16* lbase, int halfsel, int T) {
        const int koff = (T < nt) ? (T << 6) : 0;
        const u16* g = Bb_ + (size_t)(halfsel * 128 + srow) * K + koff + scol;
        u16* d = lbase + halfsel * 8192 + tid * 8;
        load16_to_lds(g, d);
        load16_to_lds(g + (size_t)64 * K, d + 4096);
    };

    // fragment read constants
    const int ar = (wm * 64 + (lane & 15)) * 64;   // + i*16*64
    const int br = (wn * 32 + (lane & 15)) * 64;   // + j*16*64
    const int x7 = lane & 7;
    const int ck = lane >> 4;
    int kp[2];
    kp[0] = ((0 + ck) ^ x7) * 8;
    kp[1] = ((4 + ck) ^ x7) * 8;

    f32x4 acc[2][2][4][2] = {};
    bf16x8 af[4][2];

    // prologue: tile0 {At,Bt,Ab,Bb} (buf0) + tile1 {At,Bt} (buf1); wait tile0
    stageA(lA, 0, 0); stageB(lB, 0, 0); stageA(lA, 1, 0); stageB(lB, 1, 0);
    stageA(lA + 16384, 0, 1); stageB(lB + 16384, 0, 1);
    asm volatile("s_waitcnt vmcnt(4)" ::: "memory");
    __builtin_amdgcn_s_barrier();

    const int iters = nt >> 1;
    for (int u = 0; u < iters; ++u) {
        #pragma unroll
        for (int th = 0; th < 2; ++th) {
            const int t   = 2 * u + th;
            const int buf = th;
            const u16* pA = lA + buf * 16384;
            const u16* pB = lB + buf * 16384;
            u16* oA = lA + (buf ^ 1) * 16384;
            u16* oB = lB + (buf ^ 1) * 16384;

            #pragma unroll
            for (int q = 0; q < 4; ++q) {
                const int mh = q >> 1, nh = q & 1;
                // ds_reads for this quadrant (A re-read when nh==0)
                if (nh == 0) {
                    #pragma unroll
                    for (int i = 0; i < 4; ++i)
                        #pragma unroll
                        for (int kk = 0; kk < 2; ++kk)
                            af[i][kk] = *(const bf16x8*)(pA + mh * 8192 + ar + i * 1024 + kp[kk]);
                }
                bf16x8 bfr[2][2];
                #pragma unroll
                for (int j = 0; j < 2; ++j)
                    #pragma unroll
                    for (int kk = 0; kk < 2; ++kk)
                        bfr[j][kk] = *(const bf16x8*)(pB + nh * 8192 + br + j * 1024 + kp[kk]);
                // stage exactly one half-tile (region freed last phase)
                if      (q == 0) stageA(oA, 1, t + 1);
                else if (q == 1) stageB(oB, 1, t + 1);
                else if (q == 2) stageA((u16*)(lA + buf * 16384), 0, t + 2);
                else             stageB((u16*)(lB + buf * 16384), 0, t + 2);
                if (nh == 0) asm volatile("s_waitcnt lgkmcnt(8)" ::: "memory");
                __builtin_amdgcn_s_barrier();
                asm volatile("s_waitcnt lgkmcnt(0)" ::: "memory");
                __builtin_amdgcn_s_setprio(1);
                #pragma unroll
                for (int i = 0; i < 4; ++i)
                    #pragma unroll
                    for (int j = 0; j < 2; ++j)
                        #pragma unroll
                        for (int kk = 0; kk < 2; ++kk)
                            acc[mh][nh][i][j] = __builtin_amdgcn_mfma_f32_16x16x32_bf16(
                                af[i][kk], bfr[j][kk], acc[mh][nh][i][j], 0, 0, 0);
                __builtin_amdgcn_s_setprio(0);
                if (q == 3) asm volatile("s_waitcnt vmcnt(4)" ::: "memory");
                __builtin_amdgcn_s_barrier();
            }
        }
    }
    asm volatile("s_waitcnt vmcnt(0)" ::: "memory");

    // epilogue: u = relu(a)^lam * exp(logprior); write + row partial sums
    // C/D layout: col = lane&15, row = (lane>>4)*4 + p   [m89/m91 verified]
    const float lam = *lambp;
    const bool lam4 = (lam == 4.0f);
    float el[2][2];
    #pragma unroll
    for (int nh = 0; nh < 2; ++nh)
        #pragma unroll
        for (int j = 0; j < 2; ++j)
            el[nh][j] = __expf(logprior[col0 + nh * 128 + wn * 32 + j * 16 + (lane & 15)]);

    #pragma unroll
    for (int mh = 0; mh < 2; ++mh) {
        #pragma unroll
        for (int i = 0; i < 4; ++i) {
            #pragma unroll
            for (int p = 0; p < 4; ++p) {
                const int m = row0 + mh * 128 + wm * 64 + i * 16 + (lane >> 4) * 4 + p;
                float* orow = Ul + (size_t)m * N + col0 + wn * 32 + (lane & 15);
                float rs = 0.f;
                #pragma unroll
                for (int nh = 0; nh < 2; ++nh) {
                    #pragma unroll
                    for (int j = 0; j < 2; ++j) {
                        float a = acc[mh][nh][i][j][p];
                        float uu = 0.f;
                        if (a > 0.f) {
                            float pw;
                            if (lam4) { float a2 = a * a; pw = a2 * a2; }
                            else      { pw = __powf(a, lam); }
                            uu = pw * el[nh][j];
                        }
                        orow[nh * 128 + j * 16] = uu;
                        rs += uu;
                    }
                }
                rs += __shfl_xor(rs, 1);
                rs += __shfl_xor(rs, 2);
                rs += __shfl_xor(rs, 4);
                rs += __shfl_xor(rs, 8);
                if ((lane & 15) == 0) atomicAdd(&rowsum[m], rs);
            }
        }
    }
}

// ---------- K3: y = ul / (rowsum + eps), grid-strided: 8 rows per block ----------
__global__ __launch_bounds__(256) void finalize_row(
    float* __restrict__ Ul, const float* __restrict__ rowsum, int nq) {
    #pragma unroll
    for (int r = 0; r < 8; ++r) {
        const size_t row = (size_t)blockIdx.x * 8 + r;
        const float inv = 1.f / (rowsum[row] + EPSN);
        float4* p = (float4*)(Ul + row * (size_t)nq * 4);
        for (int i = threadIdx.x; i < nq; i += 256) {
            float4 v = p[i];
            v.x *= inv; v.y *= inv; v.z *= inv; v.w *= inv;
            p[i] = v;
        }
    }
}

// ---------- launch ----------
static inline size_t align256(size_t x) { return (x + 255) & ~(size_t)255; }

extern "C" void kernel_launch(void* const* d_in, const int* in_sizes, int n_in,
                              void* d_out, int out_size, void* d_ws, size_t ws_size,
                              hipStream_t stream) {
    const float* x        = (const float*)d_in[0];
    const float* w        = (const float*)d_in[1];
    const float* logprior = (const float*)d_in[2];
    const float* lamb     = (const float*)d_in[3];
    const int OUT = in_sizes[2];                // 2048
    const int IN  = in_sizes[1] / OUT;          // 2048
    const int B   = in_sizes[0] / IN;           // 16384
    float* out = (float*)d_out;

    char* ws = (char*)d_ws;
    size_t off = 0;
    u16* xn = (u16*)(ws + off);         off += align256((size_t)B * IN * sizeof(u16));
    u16* wn = (u16*)(ws + off);         off += align256((size_t)OUT * IN * sizeof(u16));
    float* rowsum = (float*)(ws + off); off += align256((size_t)B * sizeof(float));

    hipMemsetAsync(rowsum, 0, (size_t)B * sizeof(float), stream);

    const int nrt = B + OUT;
    normalize_cast2<<<(nrt + 3) / 4, 256, 0, stream>>>(x, w, xn, wn, IN, B, nrt);

    const int nblk = (B / 256) * (OUT / 256);   // 512
    gemm_softhebb<<<nblk, 512, 0, stream>>>(xn, wn, logprior, lamb, out, rowsum, B, OUT, IN);

    finalize_row<<<B / 8, 256, 0, stream>>>(out, rowsum, OUT / 4);
}

// Round 6
// 457.787 us; speedup vs baseline: 1.0445x; 1.0445x over previous
//
#include <hip/hip_runtime.h>
#include <hip/hip_bf16.h>

typedef unsigned short u16;
typedef __attribute__((ext_vector_type(8))) short bf16x8;   // 8 bf16 = 4 VGPRs
typedef __attribute__((ext_vector_type(4))) float f32x4;

#define EPSN 1e-9f

// ---------- helpers ----------

__device__ __forceinline__ u16 f2bf(float f) {
    union { float f; unsigned int u; } c; c.f = f;
    unsigned int u = c.u;
    unsigned int r = (u + 0x7FFFu + ((u >> 16) & 1u)) >> 16;   // RNE
    return (u16)r;
}

__device__ __forceinline__ void load16_to_lds(const void* g, void* l) {
    __builtin_amdgcn_global_load_lds(
        (const __attribute__((address_space(1))) void*)g,
        (__attribute__((address_space(3))) void*)l,
        16, 0, 0);
}

// ---------- K1: per-row L2 normalize + cast to bf16, wave-per-row, X and W fused ----
// One 64-lane wave per row (ncols <= 2048: 8 float4 per lane). No LDS, no barriers.
__global__ __launch_bounds__(256) void normalize_cast2(
    const float* __restrict__ X, const float* __restrict__ W,
    u16* __restrict__ XO, u16* __restrict__ WO, int ncols, int nxrows, int nrt) {
    const int lane = threadIdx.x & 63;
    const int r = blockIdx.x * 4 + (threadIdx.x >> 6);
    if (r >= nrt) return;
    const float* src; u16* dst; size_t row;
    if (r < nxrows) { src = X; dst = XO; row = r; }
    else            { src = W; dst = WO; row = r - nxrows; }

    const float4* xr = (const float4*)(src + row * (size_t)ncols);
    const int nq = ncols >> 2;

    float4 v[8];
    float ss = 0.f;
    #pragma unroll
    for (int q = 0; q < 8; ++q) {
        int i = lane + q * 64;
        if (i < nq) {
            v[q] = xr[i];
            ss += v[q].x*v[q].x + v[q].y*v[q].y + v[q].z*v[q].z + v[q].w*v[q].w;
        }
    }
    #pragma unroll
    for (int o = 32; o > 0; o >>= 1) ss += __shfl_xor(ss, o);
    const float s = 1.f / (sqrtf(ss) + EPSN);

    ushort4* yr = (ushort4*)(dst + row * (size_t)ncols);
    #pragma unroll
    for (int q = 0; q < 8; ++q) {
        int i = lane + q * 64;
        if (i < nq) {
            ushort4 o4;
            o4.x = f2bf(v[q].x * s); o4.y = f2bf(v[q].y * s);
            o4.z = f2bf(v[q].z * s); o4.w = f2bf(v[q].w * s);
            yr[i] = o4;
        }
    }
}

// ---------- K2: bf16 MFMA GEMM (A[M,K] * B[N,K]^T) + fused relu/pow epilogue ----------
// PROVEN 2-phase core (157 us, MfmaUtil 39%): 128x128 tile, BK=64, 4 waves each
// computing 64x64 via 4x4 grid of 16x16x32 MFMA. LDS XOR-swizzle: chunk (row, kc)
// of 8 bf16 stored at position kc ^ (row&7) -> global_load_lds stays contiguous,
// ds_read_b128 is 2-way max (measured 0 bank conflicts).
// NEW vs round-4 (only change): 1D grid + column-stripe XCD swizzle. XCD x owns
// B-column-panels {2x,2x+1} (0.5 MB each -> L2-resident) and streams all of A
// (L3-absorbed, HBM-fetched once). Round-5 measured this locality pattern at
// FETCH 103 MB vs 300 MB for the unswizzled 2D grid; the per-K-step vmcnt(0)
// drain waits on these loads, so L2/L3 hits shorten the structural stall.
#define BK 64

__global__ __launch_bounds__(256, 2) void gemm_softhebb(
    const u16* __restrict__ A, const u16* __restrict__ B,
    const float* __restrict__ logprior, const float* __restrict__ lambp,
    float* __restrict__ Ul, float* __restrict__ rowsum,
    int M, int N, int K) {
    __shared__ __align__(16) u16 lA[128 * BK];
    __shared__ __align__(16) u16 lB[128 * BK];

    const int tid  = threadIdx.x;
    const int lane = tid & 63;
    const int wm   = (tid >> 6) & 1;   // wave row (0..1)
    const int wn   = tid >> 7;         // wave col (0..1)

    // XCD column-stripe swizzle (grid = ntm*ntn blocks, ntm*ntn % 8 == 0):
    // dispatch round-robins linear id across 8 XCDs; remap so XCD x gets the
    // contiguous wg range [x*chunk, (x+1)*chunk) which walks all row tiles of
    // its own column panels.
    const int ntm = M >> 7;                      // 128
    const int ntn = N >> 7;                      // 16
    int wg = blockIdx.x;
    wg = (wg & 7) * ((ntm * ntn) >> 3) + (wg >> 3);
    const int tn = wg / ntm;                     // column tile (slow: per-XCD)
    const int tm = wg - tn * ntm;                // row tile (fast: streams A)
    const int row0 = tm << 7;
    const int col0 = tn << 7;

    f32x4 acc[4][4] = {};

    // staging indices: chunk c = p*256+tid; row=c>>3, stored pos=c&7,
    // global kchunk = (c&7) ^ (row&7)
    const u16* ap[4];
    const u16* bp[4];
    #pragma unroll
    for (int p = 0; p < 4; ++p) {
        int c = p * 256 + tid;
        int r = c >> 3;
        int o = ((c & 7) ^ (r & 7)) * 8;
        ap[p] = A + (size_t)(row0 + r) * K + o;
        bp[p] = B + (size_t)(col0 + r) * K + o;
    }

    for (int k0 = 0; k0 < K; k0 += BK) {
        #pragma unroll
        for (int p = 0; p < 4; ++p) {
            int c = p * 256 + tid;
            load16_to_lds(ap[p] + k0, &lA[c * 8]);
            load16_to_lds(bp[p] + k0, &lB[c * 8]);
        }
        __syncthreads();

        #pragma unroll
        for (int s = 0; s < 2; ++s) {
            // fragment row r has (r&7)==(lane&7); kchunk = s*4 + (lane>>4)
            const int pos = (((s << 2) + (lane >> 4)) ^ (lane & 7)) * 8;
            bf16x8 af[4], bfr[4];
            #pragma unroll
            for (int i = 0; i < 4; ++i) {
                int r = wm * 64 + i * 16 + (lane & 15);
                af[i] = *(const bf16x8*)&lA[r * 64 + pos];
            }
            #pragma unroll
            for (int j = 0; j < 4; ++j) {
                int r = wn * 64 + j * 16 + (lane & 15);
                bfr[j] = *(const bf16x8*)&lB[r * 64 + pos];
            }
            #pragma unroll
            for (int i = 0; i < 4; ++i)
                #pragma unroll
                for (int j = 0; j < 4; ++j)
                    acc[i][j] = __builtin_amdgcn_mfma_f32_16x16x32_bf16(
                        af[i], bfr[j], acc[i][j], 0, 0, 0);
        }
        __syncthreads();
    }

    // epilogue: u = relu(a); ul = u^lam * exp(logprior); write + row partial sums
    // C/D layout: col = lane&15, row = (lane>>4)*4 + p   [m89/m91 verified]
    const float lam = *lambp;
    const bool lam4 = (lam == 4.0f);
    float el[4];
    #pragma unroll
    for (int j = 0; j < 4; ++j)
        el[j] = __expf(logprior[col0 + wn * 64 + j * 16 + (lane & 15)]);

    #pragma unroll
    for (int i = 0; i < 4; ++i) {
        #pragma unroll
        for (int p = 0; p < 4; ++p) {
            const int m = row0 + wm * 64 + i * 16 + (lane >> 4) * 4 + p;
            float* outrow = Ul + (size_t)m * N + col0 + wn * 64 + (lane & 15);
            float rs = 0.f;
            #pragma unroll
            for (int j = 0; j < 4; ++j) {
                float a = acc[i][j][p];
                float u = 0.f;
                if (a > 0.f) {
                    float pw;
                    if (lam4) { float a2 = a * a; pw = a2 * a2; }
                    else      { pw = __powf(a, lam); }
                    u = pw * el[j];
                }
                outrow[j * 16] = u;
                rs += u;
            }
            // reduce across the 16 lanes sharing this row (lanes differ in low 4 bits)
            rs += __shfl_xor(rs, 1);
            rs += __shfl_xor(rs, 2);
            rs += __shfl_xor(rs, 4);
            rs += __shfl_xor(rs, 8);
            if ((lane & 15) == 0) atomicAdd(&rowsum[m], rs);
        }
    }
}

// ---------- K3: y = ul / (rowsum + eps), grid-strided: 8 rows per block ----------
__global__ __launch_bounds__(256) void finalize_row(
    float* __restrict__ Ul, const float* __restrict__ rowsum, int nq) {
    #pragma unroll
    for (int r = 0; r < 8; ++r) {
        const size_t row = (size_t)blockIdx.x * 8 + r;
        const float inv = 1.f / (rowsum[row] + EPSN);
        float4* p = (float4*)(Ul + row * (size_t)nq * 4);
        for (int i = threadIdx.x; i < nq; i += 256) {
            float4 v = p[i];
            v.x *= inv; v.y *= inv; v.z *= inv; v.w *= inv;
            p[i] = v;
        }
    }
}

// ---------- launch ----------
static inline size_t align256(size_t x) { return (x + 255) & ~(size_t)255; }

extern "C" void kernel_launch(void* const* d_in, const int* in_sizes, int n_in,
                              void* d_out, int out_size, void* d_ws, size_t ws_size,
                              hipStream_t stream) {
    const float* x        = (const float*)d_in[0];
    const float* w        = (const float*)d_in[1];
    const float* logprior = (const float*)d_in[2];
    const float* lamb     = (const float*)d_in[3];
    const int OUT = in_sizes[2];                // 2048
    const int IN  = in_sizes[1] / OUT;          // 2048
    const int B   = in_sizes[0] / IN;           // 16384
    float* out = (float*)d_out;

    char* ws = (char*)d_ws;
    size_t off = 0;
    u16* xn = (u16*)(ws + off);         off += align256((size_t)B * IN * sizeof(u16));
    u16* wn = (u16*)(ws + off);         off += align256((size_t)OUT * IN * sizeof(u16));
    float* rowsum = (float*)(ws + off); off += align256((size_t)B * sizeof(float));

    hipMemsetAsync(rowsum, 0, (size_t)B * sizeof(float), stream);

    const int nrt = B + OUT;
    normalize_cast2<<<(nrt + 3) / 4, 256, 0, stream>>>(x, w, xn, wn, IN, B, nrt);

    const int nblk = (B / 128) * (OUT / 128);   // 2048 (divisible by 8)
    gemm_softhebb<<<nblk, 256, 0, stream>>>(xn, wn, logprior, lamb, out, rowsum, B, OUT, IN);

    finalize_row<<<B / 8, 256, 0, stream>>>(out, rowsum, OUT / 4);
}

// Round 7
// 419.294 us; speedup vs baseline: 1.1404x; 1.0918x over previous
//
#include <hip/hip_runtime.h>
#include <hip/hip_bf16.h>

typedef unsigned short u16;
typedef __attribute__((ext_vector_type(8))) short bf16x8;   // 8 bf16 = 4 VGPRs
typedef __attribute__((ext_vector_type(4))) float f32x4;

#define EPSN 1e-9f

// ---------- helpers ----------

__device__ __forceinline__ u16 f2bf(float f) {
    union { float f; unsigned int u; } c; c.f = f;
    unsigned int u = c.u;
    unsigned int r = (u + 0x7FFFu + ((u >> 16) & 1u)) >> 16;   // RNE
    return (u16)r;
}

__device__ __forceinline__ void load16_to_lds(const void* g, void* l) {
    __builtin_amdgcn_global_load_lds(
        (const __attribute__((address_space(1))) void*)g,
        (__attribute__((address_space(3))) void*)l,
        16, 0, 0);
}

// ---------- K1: per-row L2 normalize + cast to bf16, wave-per-row, X and W fused ----
// One 64-lane wave per row (ncols <= 2048: 8 float4 per lane). No LDS, no barriers.
// Also zeroes rowsum[r] for X-rows (replaces the hipMemsetAsync dispatch; stream
// order guarantees completion before the GEMM's atomics).
__global__ __launch_bounds__(256) void normalize_cast2(
    const float* __restrict__ X, const float* __restrict__ W,
    u16* __restrict__ XO, u16* __restrict__ WO, float* __restrict__ rowsum,
    int ncols, int nxrows, int nrt) {
    const int lane = threadIdx.x & 63;
    const int r = blockIdx.x * 4 + (threadIdx.x >> 6);
    if (r >= nrt) return;
    const float* src; u16* dst; size_t row;
    if (r < nxrows) { src = X; dst = XO; row = r; if (lane == 0) rowsum[r] = 0.f; }
    else            { src = W; dst = WO; row = r - nxrows; }

    const float4* xr = (const float4*)(src + row * (size_t)ncols);
    const int nq = ncols >> 2;

    float4 v[8];
    float ss = 0.f;
    #pragma unroll
    for (int q = 0; q < 8; ++q) {
        int i = lane + q * 64;
        if (i < nq) {
            v[q] = xr[i];
            ss += v[q].x*v[q].x + v[q].y*v[q].y + v[q].z*v[q].z + v[q].w*v[q].w;
        }
    }
    #pragma unroll
    for (int o = 32; o > 0; o >>= 1) ss += __shfl_xor(ss, o);
    const float s = 1.f / (sqrtf(ss) + EPSN);

    ushort4* yr = (ushort4*)(dst + row * (size_t)ncols);
    #pragma unroll
    for (int q = 0; q < 8; ++q) {
        int i = lane + q * 64;
        if (i < nq) {
            ushort4 o4;
            o4.x = f2bf(v[q].x * s); o4.y = f2bf(v[q].y * s);
            o4.z = f2bf(v[q].z * s); o4.w = f2bf(v[q].w * s);
            yr[i] = o4;
        }
    }
}

// ---------- K2: bf16 MFMA GEMM (A[M,K] * B[N,K]^T) + fused relu/pow epilogue ----------
// PROVEN 2-phase core (157 us, MfmaUtil 39%, = the ~900 TF structural ceiling of
// this schedule): 128x128 tile, BK=64, 4 waves each computing 64x64 via 4x4 grid
// of 16x16x32 MFMA. LDS XOR-swizzle: chunk (row, kc) of 8 bf16 stored at position
// kc ^ (row&7) -> global_load_lds stays contiguous, ds_read_b128 2-way max
// (measured 0 bank conflicts). Default 2D grid: all 16 column-tiles of a row
// panel dispatch consecutively -> A-panel fetched once, L3-shared (measured best;
// both attempted XCD remaps increased HBM fetch and regressed 19-30%).
#define BK 64

__global__ __launch_bounds__(256, 2) void gemm_softhebb(
    const u16* __restrict__ A, const u16* __restrict__ B,
    const float* __restrict__ logprior, const float* __restrict__ lambp,
    float* __restrict__ Ul, float* __restrict__ rowsum,
    int M, int N, int K) {
    __shared__ __align__(16) u16 lA[128 * BK];
    __shared__ __align__(16) u16 lB[128 * BK];

    const int tid  = threadIdx.x;
    const int lane = tid & 63;
    const int wm   = (tid >> 6) & 1;   // wave row (0..1)
    const int wn   = tid >> 7;         // wave col (0..1)
    const int row0 = blockIdx.y * 128;
    const int col0 = blockIdx.x * 128;

    f32x4 acc[4][4] = {};

    // staging indices: chunk c = p*256+tid; row=c>>3, stored pos=c&7,
    // global kchunk = (c&7) ^ (row&7)
    const u16* ap[4];
    const u16* bp[4];
    #pragma unroll
    for (int p = 0; p < 4; ++p) {
        int c = p * 256 + tid;
        int r = c >> 3;
        int o = ((c & 7) ^ (r & 7)) * 8;
        ap[p] = A + (size_t)(row0 + r) * K + o;
        bp[p] = B + (size_t)(col0 + r) * K + o;
    }

    for (int k0 = 0; k0 < K; k0 += BK) {
        #pragma unroll
        for (int p = 0; p < 4; ++p) {
            int c = p * 256 + tid;
            load16_to_lds(ap[p] + k0, &lA[c * 8]);
            load16_to_lds(bp[p] + k0, &lB[c * 8]);
        }
        __syncthreads();

        #pragma unroll
        for (int s = 0; s < 2; ++s) {
            // fragment row r has (r&7)==(lane&7); kchunk = s*4 + (lane>>4)
            const int pos = (((s << 2) + (lane >> 4)) ^ (lane & 7)) * 8;
            bf16x8 af[4], bfr[4];
            #pragma unroll
            for (int i = 0; i < 4; ++i) {
                int r = wm * 64 + i * 16 + (lane & 15);
                af[i] = *(const bf16x8*)&lA[r * 64 + pos];
            }
            #pragma unroll
            for (int j = 0; j < 4; ++j) {
                int r = wn * 64 + j * 16 + (lane & 15);
                bfr[j] = *(const bf16x8*)&lB[r * 64 + pos];
            }
            #pragma unroll
            for (int i = 0; i < 4; ++i)
                #pragma unroll
                for (int j = 0; j < 4; ++j)
                    acc[i][j] = __builtin_amdgcn_mfma_f32_16x16x32_bf16(
                        af[i], bfr[j], acc[i][j], 0, 0, 0);
        }
        __syncthreads();
    }

    // epilogue: u = relu(a); ul = u^lam * exp(logprior); write + row partial sums
    // C/D layout: col = lane&15, row = (lane>>4)*4 + p   [m89/m91 verified]
    const float lam = *lambp;
    const bool lam4 = (lam == 4.0f);
    float el[4];
    #pragma unroll
    for (int j = 0; j < 4; ++j)
        el[j] = __expf(logprior[col0 + wn * 64 + j * 16 + (lane & 15)]);

    #pragma unroll
    for (int i = 0; i < 4; ++i) {
        #pragma unroll
        for (int p = 0; p < 4; ++p) {
            const int m = row0 + wm * 64 + i * 16 + (lane >> 4) * 4 + p;
            float* outrow = Ul + (size_t)m * N + col0 + wn * 64 + (lane & 15);
            float rs = 0.f;
            #pragma unroll
            for (int j = 0; j < 4; ++j) {
                float a = acc[i][j][p];
                float u = 0.f;
                if (a > 0.f) {
                    float pw;
                    if (lam4) { float a2 = a * a; pw = a2 * a2; }
                    else      { pw = __powf(a, lam); }
                    u = pw * el[j];
                }
                outrow[j * 16] = u;
                rs += u;
            }
            // reduce across the 16 lanes sharing this row (lanes differ in low 4 bits)
            rs += __shfl_xor(rs, 1);
            rs += __shfl_xor(rs, 2);
            rs += __shfl_xor(rs, 4);
            rs += __shfl_xor(rs, 8);
            if ((lane & 15) == 0) atomicAdd(&rowsum[m], rs);
        }
    }
}

// ---------- K3: y = ul / (rowsum + eps), grid-strided: 8 rows per block ----------
__global__ __launch_bounds__(256) void finalize_row(
    float* __restrict__ Ul, const float* __restrict__ rowsum, int nq) {
    #pragma unroll
    for (int r = 0; r < 8; ++r) {
        const size_t row = (size_t)blockIdx.x * 8 + r;
        const float inv = 1.f / (rowsum[row] + EPSN);
        float4* p = (float4*)(Ul + row * (size_t)nq * 4);
        for (int i = threadIdx.x; i < nq; i += 256) {
            float4 v = p[i];
            v.x *= inv; v.y *= inv; v.z *= inv; v.w *= inv;
            p[i] = v;
        }
    }
}

// ---------- launch ----------
static inline size_t align256(size_t x) { return (x + 255) & ~(size_t)255; }

extern "C" void kernel_launch(void* const* d_in, const int* in_sizes, int n_in,
                              void* d_out, int out_size, void* d_ws, size_t ws_size,
                              hipStream_t stream) {
    const float* x        = (const float*)d_in[0];
    const float* w        = (const float*)d_in[1];
    const float* logprior = (const float*)d_in[2];
    const float* lamb     = (const float*)d_in[3];
    const int OUT = in_sizes[2];                // 2048
    const int IN  = in_sizes[1] / OUT;          // 2048
    const int B   = in_sizes[0] / IN;           // 16384
    float* out = (float*)d_out;

    char* ws = (char*)d_ws;
    size_t off = 0;
    u16* xn = (u16*)(ws + off);         off += align256((size_t)B * IN * sizeof(u16));
    u16* wn = (u16*)(ws + off);         off += align256((size_t)OUT * IN * sizeof(u16));
    float* rowsum = (float*)(ws + off); off += align256((size_t)B * sizeof(float));

    const int nrt = B + OUT;
    normalize_cast2<<<(nrt + 3) / 4, 256, 0, stream>>>(x, w, xn, wn, rowsum, IN, B, nrt);

    dim3 grid(OUT / 128, B / 128);
    gemm_softhebb<<<grid, 256, 0, stream>>>(xn, wn, logprior, lamb, out, rowsum, B, OUT, IN);

    finalize_row<<<B / 8, 256, 0, stream>>>(out, rowsum, OUT / 4);
}